// Round 5
// baseline (862.013 us; speedup 1.0000x reference)
//
#include <hip/hip_runtime.h>
#include <stdint.h>

// Problem constants
constexpr int B_ = 8, N_ = 4096, E_ = 2048, C_ = 128;
constexpr int CN = 144;   // 128 channels + 1 ones-col + 15 pad
constexpr int KT = 32;    // K per MFMA step
constexpr int MT = 32;    // M rows per block (2 x 16-row groups)
constexpr int NWK = 4;    // K-split across the 4 waves of a block
constexpr int LRF = 145;  // reduction LDS row stride (floats)

typedef short bf16x8 __attribute__((ext_vector_type(8)));
typedef float f32x4  __attribute__((ext_vector_type(4)));

__device__ inline uint16_t bf16_rne(float f) {
    uint32_t u = __builtin_bit_cast(uint32_t, f);
    return (uint16_t)((u + 0x7FFFu + ((u >> 16) & 1u)) >> 16);
}

constexpr size_t HT_E  = (size_t)B_ * (N_ / 32) * E_;  // 2M dwords = 8 MB
constexpr size_t WT_E  = (size_t)CN * C_;
constexpr size_t EBF_E = (size_t)B_ * CN * E_;

// ---------------------------------------------------------------------------
// pack: H (fp32 0/1) -> HT[b][n/32][e], bit i of word = H[b][32*(n/32)+i][e].
// Coalesced reads (1 KB/row-step/block) and fully coalesced writes.
// ---------------------------------------------------------------------------
__global__ void pack_kernel(const float* __restrict__ H, uint32_t* __restrict__ HT) {
    const int t  = threadIdx.x;
    const int eg = blockIdx.x & 7;
    const int ng = (blockIdx.x >> 3) & 127;
    const int b  = blockIdx.x >> 10;
    const int e  = eg * 256 + t;
    const float* hp = H + ((size_t)b * N_ + ng * 32) * E_ + e;
    uint32_t w = 0;
#pragma unroll
    for (int i = 0; i < 32; ++i) w |= (hp[(size_t)i * E_] > 0.5f) ? (1u << i) : 0u;
    HT[((size_t)b * (N_ / 32) + ng) * E_ + e] = w;
}

// ---------------------------------------------------------------------------
// prep: WTb = bf16(W^T) padded to 144 rows; constant rows 128..143 of xwbT
// (in d_out) and ebfT (ws): row 128 = 1.0 (ones-col -> s_e / d_n), rest 0.
// ---------------------------------------------------------------------------
__global__ void prep_kernel(const float* __restrict__ W, uint16_t* __restrict__ WTb,
                            uint32_t* __restrict__ xwbT32, uint32_t* __restrict__ ebfT32) {
    const int NW = (int)WT_E;                  // 18432
    const int NX = B_ * 16 * (N_ / 2);         // 262144 dwords
    const int NE = B_ * 16 * (E_ / 2);         // 131072 dwords
    int stride = gridDim.x * blockDim.x;
    for (int i = blockIdx.x * blockDim.x + threadIdx.x; i < NW + NX + NE; i += stride) {
        if (i < NW) {
            int c = i >> 7, k = i & 127;
            WTb[i] = bf16_rne((c < C_) ? W[k * C_ + c] : 0.f);
        } else if (i < NW + NX) {
            int j = i - NW;
            int b = j >> 15, rr = j & 32767;
            int r = rr >> 11, n2 = rr & 2047;
            xwbT32[((size_t)b * CN + (C_ + r)) * (N_ / 2) + n2] = (r == 0) ? 0x3F803F80u : 0u;
        } else {
            int j = i - NW - NX;
            int b = j >> 14, rr = j & 16383;
            int r = rr >> 10, e2 = rr & 1023;
            ebfT32[((size_t)b * CN + (C_ + r)) * (E_ / 2) + e2] = (r == 0) ? 0x3F803F80u : 0u;
        }
    }
}

// ---------------------------------------------------------------------------
// Barrier-free MFMA GEMM. 256 thr = 4 waves; waves split K (NOT M); no LDS in
// the main loop; per-lane A from bit words, per-lane B as aligned b128 global
// loads (L2-resident panels). End: 3-barrier LDS reduction + wave0 epilogue.
//  MODE 0 (fc) : A = x fp32,    B = WTb,  out bf16 C^T xwbT (+bias)
//  MODE 1 (v2e): A = H^T bits,  B = xwbT, out bf16 C^T ebfT (x 1/s_e)
//  MODE 2 (e2v): A = H bits,    B = ebfT, out fp32 row-major (x 1/d_n)
// ---------------------------------------------------------------------------
template <int MODE>
__global__ __launch_bounds__(256, 2)
void gemm_k(const float* __restrict__ Ax, const uint32_t* __restrict__ HT,
            const uint16_t* __restrict__ Btb, const float* __restrict__ bias,
            uint16_t* __restrict__ outT, float* __restrict__ outF) {
    constexpr int K  = (MODE == 0) ? C_ : (MODE == 1) ? N_ : E_;
    constexpr int KW = K / NWK;                 // per-wave K chunk
    constexpr int SW = KW / KT;                 // 1 / 32 / 16 iterations
    constexpr size_t BBS = (MODE == 0) ? 0 : (size_t)CN * K;
    constexpr int OLD = (MODE == 0) ? N_ : E_;

    __shared__ float R[2 * 32 * LRF];           // two 32x144 reduction regions

    const int t = threadIdx.x, wave = t >> 6, lane = t & 63;
    const int l15 = lane & 15, quad = lane >> 4;
    const int batch = blockIdx.x & 7;           // XCD spread: panels stay in one L2
    const int m0 = (blockIdx.x >> 3) * MT;
    const int kw = wave * KW;

    const uint16_t* Bp = Btb + (size_t)batch * BBS;
    const uint32_t* Hp = HT + (size_t)batch * (N_ / 32) * E_;

    f32x4 acc[18];
#pragma unroll
    for (int i = 0; i < 18; ++i) acc[i] = (f32x4){0.f, 0.f, 0.f, 0.f};

    float    af[2][2][8];   // MODE 0
    uint32_t aw1[2][2];     // MODE 1: one word per 16-row group
    uint4    aw2[2][2];     // MODE 2: 8 consecutive e-words (32B, quad-uniform)
    bf16x8   bfr[2][9];

    auto loadA = [&](int k0, int buf) {
        if constexpr (MODE == 0) {
#pragma unroll
            for (int g = 0; g < 2; ++g) {
                const float* ap = Ax + ((size_t)batch * N_ + m0 + g * 16 + l15) * C_ + k0 + quad * 8;
                const float4 f0 = *(const float4*)ap;
                const float4 f1 = *(const float4*)(ap + 4);
                af[buf][g][0] = f0.x; af[buf][g][1] = f0.y; af[buf][g][2] = f0.z; af[buf][g][3] = f0.w;
                af[buf][g][4] = f1.x; af[buf][g][5] = f1.y; af[buf][g][6] = f1.z; af[buf][g][7] = f1.w;
            }
        } else if constexpr (MODE == 1) {
            const uint32_t* p = Hp + (size_t)(k0 >> 5) * E_ + m0 + l15;
            aw1[buf][0] = p[0];
            aw1[buf][1] = p[16];
        } else {
            const uint32_t* p = Hp + (size_t)(m0 >> 5) * E_ + k0 + quad * 8;
            aw2[buf][0] = *(const uint4*)p;
            aw2[buf][1] = *(const uint4*)(p + 4);
        }
    };
    auto loadB = [&](int k0, int buf) {
#pragma unroll
        for (int j = 0; j < 9; ++j)
            bfr[buf][j] = *(const bf16x8*)&Bp[(size_t)(j * 16 + l15) * K + k0 + quad * 8];
    };
    auto mk_afrag = [&](int buf, int g) -> bf16x8 {
        bf16x8 v;
        if constexpr (MODE == 0) {
#pragma unroll
            for (int jj = 0; jj < 8; ++jj) v[jj] = (short)bf16_rne(af[buf][g][jj]);
        } else if constexpr (MODE == 1) {
            const uint32_t w = aw1[buf][g];
            const int base = quad * 8;
#pragma unroll
            for (int jj = 0; jj < 8; ++jj)
                v[jj] = (short)(((w >> (base + jj)) & 1u) ? 0x3F80 : 0);
        } else {
            const int bit = g * 16 + l15;
            const uint32_t u[8] = {aw2[buf][0].x, aw2[buf][0].y, aw2[buf][0].z, aw2[buf][0].w,
                                   aw2[buf][1].x, aw2[buf][1].y, aw2[buf][1].z, aw2[buf][1].w};
#pragma unroll
            for (int jj = 0; jj < 8; ++jj)
                v[jj] = (short)(((u[jj] >> bit) & 1u) ? 0x3F80 : 0);
        }
        return v;
    };

    loadA(kw, 0); loadB(kw, 0);
#pragma unroll 1
    for (int s = 0; s < SW; ++s) {
        const int cb = s & 1;
        if (s + 1 < SW) { loadA(kw + (s + 1) * KT, cb ^ 1); loadB(kw + (s + 1) * KT, cb ^ 1); }
        bf16x8 a0 = mk_afrag(cb, 0);
        bf16x8 a1 = mk_afrag(cb, 1);
#pragma unroll
        for (int j = 0; j < 9; ++j) {
            acc[j]     = __builtin_amdgcn_mfma_f32_16x16x32_bf16(a0, bfr[cb][j], acc[j],     0, 0, 0);
            acc[9 + j] = __builtin_amdgcn_mfma_f32_16x16x32_bf16(a1, bfr[cb][j], acc[9 + j], 0, 0, 0);
        }
    }

    // ---- cross-wave K reduction (3 barriers total) ----
    auto stR = [&](int base) {
#pragma unroll
        for (int g = 0; g < 2; ++g)
#pragma unroll
            for (int j = 0; j < 9; ++j)
#pragma unroll
                for (int r = 0; r < 4; ++r)
                    R[base + (g * 16 + quad * 4 + r) * LRF + j * 16 + l15] = acc[g * 9 + j][r];
    };
    auto ldR = [&](int base) {
#pragma unroll
        for (int g = 0; g < 2; ++g)
#pragma unroll
            for (int j = 0; j < 9; ++j)
#pragma unroll
                for (int r = 0; r < 4; ++r)
                    acc[g * 9 + j][r] += R[base + (g * 16 + quad * 4 + r) * LRF + j * 16 + l15];
    };
    if (wave == 1) stR(0);
    if (wave == 3) stR(32 * LRF);
    __syncthreads();
    if (wave == 0) ldR(0);
    if (wave == 2) ldR(32 * LRF);
    __syncthreads();
    if (wave == 2) stR(0);
    __syncthreads();
    if (wave != 0) return;
    ldR(0);

    // ---- epilogue (wave 0) ----
    float mul[2][4];
    if constexpr (MODE != 0) {
#pragma unroll
        for (int g = 0; g < 2; ++g)
#pragma unroll
            for (int r = 0; r < 4; ++r) {
                float sv = __shfl(acc[g * 9 + 8][r], lane & 48);  // lane quad*16 holds col 128
                mul[g][r] = (sv > 0.f) ? 1.f / sv : 0.f;
            }
    }
#pragma unroll
    for (int g = 0; g < 2; ++g) {
        const int row = m0 + g * 16 + quad * 4;
        if constexpr (MODE == 2) {
            float* op = outF + ((size_t)batch * N_ + row) * C_;
#pragma unroll
            for (int j = 0; j < 8; ++j) {
                int c = j * 16 + l15;
#pragma unroll
                for (int r = 0; r < 4; ++r) op[(size_t)r * C_ + c] = acc[g * 9 + j][r] * mul[g][r];
            }
        } else {
#pragma unroll
            for (int j = 0; j < 8; ++j) {
                int c = j * 16 + l15;
                float v0, v1, v2, v3;
                if constexpr (MODE == 0) {
                    float bb = bias[c];
                    v0 = acc[g * 9 + j][0] + bb; v1 = acc[g * 9 + j][1] + bb;
                    v2 = acc[g * 9 + j][2] + bb; v3 = acc[g * 9 + j][3] + bb;
                } else {
                    v0 = acc[g * 9 + j][0] * mul[g][0]; v1 = acc[g * 9 + j][1] * mul[g][1];
                    v2 = acc[g * 9 + j][2] * mul[g][2]; v3 = acc[g * 9 + j][3] * mul[g][3];
                }
                uint32_t q0 = (uint32_t)bf16_rne(v0) | ((uint32_t)bf16_rne(v1) << 16);
                uint32_t q1 = (uint32_t)bf16_rne(v2) | ((uint32_t)bf16_rne(v3) << 16);
                uint16_t* op = outT + ((size_t)batch * CN + c) * OLD + row;
                *(uint2*)op = make_uint2(q0, q1);
            }
        }
    }
}

// ---------------------------------------------------------------------------
extern "C" void kernel_launch(void* const* d_in, const int* in_sizes, int n_in,
                              void* d_out, int out_size, void* d_ws, size_t ws_size,
                              hipStream_t stream) {
    const float* x    = (const float*)d_in[0];   // [8,4096,128]
    const float* H    = (const float*)d_in[1];   // [8,4096,2048]
    const float* W    = (const float*)d_in[2];   // [128,128]
    const float* bias = (const float*)d_in[3];   // [128]
    float* out = (float*)d_out;                  // [8,4096,128]

    // ws (~12.8 MB): HT (8 MB) | WTb (36 KB) | ebfT (4.7 MB)
    uint32_t* HT   = (uint32_t*)d_ws;
    uint16_t* WTb  = (uint16_t*)(HT + HT_E);
    uint16_t* ebfT = WTb + WT_E;
    uint16_t* xwbT = (uint16_t*)d_out;           // d_out is dead scratch until e2v

    pack_kernel<<<dim3(8192), dim3(256), 0, stream>>>(H, HT);
    prep_kernel<<<dim3(1024), dim3(256), 0, stream>>>(W, WTb, (uint32_t*)xwbT, (uint32_t*)ebfT);
    gemm_k<0><<<dim3(8 * (N_ / MT)), dim3(256), 0, stream>>>(x, nullptr, WTb, bias, xwbT, nullptr);
    gemm_k<1><<<dim3(8 * (E_ / MT)), dim3(256), 0, stream>>>(nullptr, HT, xwbT, nullptr, ebfT, nullptr);
    gemm_k<2><<<dim3(8 * (N_ / MT)), dim3(256), 0, stream>>>(nullptr, HT, ebfT, nullptr, nullptr, out);
}

// Round 6
// 524.229 us; speedup vs baseline: 1.6443x; 1.6443x over previous
//
#include <hip/hip_runtime.h>
#include <stdint.h>

// Problem constants
constexpr int B_ = 8, N_ = 4096, E_ = 2048, C_ = 128;
constexpr int CN = 144;   // 128 channels + 1 ones-col + 15 pad
constexpr int KT = 32;    // K per MFMA step
constexpr int MT = 32;    // M rows per block (2 x 16-row groups)
constexpr int NWK = 4;    // K-split across the 4 waves of a block
constexpr int LRF = 145;  // reduction LDS row stride (floats)

typedef short bf16x8 __attribute__((ext_vector_type(8)));
typedef float f32x4  __attribute__((ext_vector_type(4)));

__device__ inline uint16_t bf16_rne(float f) {
    uint32_t u = __builtin_bit_cast(uint32_t, f);
    return (uint16_t)((u + 0x7FFFu + ((u >> 16) & 1u)) >> 16);
}

constexpr size_t HT_E  = (size_t)B_ * (N_ / 32) * E_;  // 2M dwords = 8 MB
constexpr size_t WT_E  = (size_t)CN * C_;
constexpr size_t EBF_E = (size_t)B_ * CN * E_;

// ---------------------------------------------------------------------------
// pack: H (fp32 0/1) -> HT[b][n/32][e], bit i of word = H[b][32*(n/32)+i][e].
// HBM-bound: reads the irreducible 268 MB once.
// ---------------------------------------------------------------------------
__global__ void pack_kernel(const float* __restrict__ H, uint32_t* __restrict__ HT) {
    const int t  = threadIdx.x;
    const int eg = blockIdx.x & 7;
    const int ng = (blockIdx.x >> 3) & 127;
    const int b  = blockIdx.x >> 10;
    const int e  = eg * 256 + t;
    const float* hp = H + ((size_t)b * N_ + ng * 32) * E_ + e;
    uint32_t w = 0;
#pragma unroll
    for (int i = 0; i < 32; ++i) w |= (hp[(size_t)i * E_] > 0.5f) ? (1u << i) : 0u;
    HT[((size_t)b * (N_ / 32) + ng) * E_ + e] = w;
}

// ---------------------------------------------------------------------------
// prep: WTb = bf16(W^T) padded to 144 rows; constant rows 128..143 of xwbT
// (in d_out) and ebfT (ws): row 128 = 1.0 (ones-col -> s_e / d_n), rest 0.
// ---------------------------------------------------------------------------
__global__ void prep_kernel(const float* __restrict__ W, uint16_t* __restrict__ WTb,
                            uint32_t* __restrict__ xwbT32, uint32_t* __restrict__ ebfT32) {
    const int NW = (int)WT_E;                  // 18432
    const int NX = B_ * 16 * (N_ / 2);         // 262144 dwords
    const int NE = B_ * 16 * (E_ / 2);         // 131072 dwords
    int stride = gridDim.x * blockDim.x;
    for (int i = blockIdx.x * blockDim.x + threadIdx.x; i < NW + NX + NE; i += stride) {
        if (i < NW) {
            int c = i >> 7, k = i & 127;
            WTb[i] = bf16_rne((c < C_) ? W[k * C_ + c] : 0.f);
        } else if (i < NW + NX) {
            int j = i - NW;
            int b = j >> 15, rr = j & 32767;
            int r = rr >> 11, n2 = rr & 2047;
            xwbT32[((size_t)b * CN + (C_ + r)) * (N_ / 2) + n2] = (r == 0) ? 0x3F803F80u : 0u;
        } else {
            int j = i - NW - NX;
            int b = j >> 14, rr = j & 16383;
            int r = rr >> 10, e2 = rr & 1023;
            ebfT32[((size_t)b * CN + (C_ + r)) * (E_ / 2) + e2] = (r == 0) ? 0x3F803F80u : 0u;
        }
    }
}

// ---------------------------------------------------------------------------
// Barrier-free MFMA GEMM. 256 thr = 4 waves; waves split K; no LDS in the main
// loop; per-lane A from bit words, per-lane B as aligned b128 global loads
// (L2-resident panels). End: 3-barrier LDS reduction + wave0 epilogue.
// ALL prefetch buffers indexed with LITERAL constants (round-5 scratch bug fix).
//  MODE 0 (fc) : A = x fp32,    B = WTb,  out bf16 C^T xwbT (+bias)
//  MODE 1 (v2e): A = H^T bits,  B = xwbT, out bf16 C^T ebfT (x 1/s_e)
//  MODE 2 (e2v): A = H bits,    B = ebfT, out fp32 row-major (x 1/d_n)
// ---------------------------------------------------------------------------
template <int MODE>
__global__ __launch_bounds__(256, 2)
void gemm_k(const float* __restrict__ Ax, const uint32_t* __restrict__ HT,
            const uint16_t* __restrict__ Btb, const float* __restrict__ bias,
            uint16_t* __restrict__ outT, float* __restrict__ outF) {
    constexpr int K  = (MODE == 0) ? C_ : (MODE == 1) ? N_ : E_;
    constexpr int KW = K / NWK;                 // per-wave K chunk
    constexpr int SW = KW / KT;                 // 1 / 32 / 16 iterations
    constexpr size_t BBS = (MODE == 0) ? 0 : (size_t)CN * K;
    constexpr int OLD = (MODE == 0) ? N_ : E_;

    __shared__ float R[2 * 32 * LRF];           // two 32x144 reduction regions

    const int t = threadIdx.x, wave = t >> 6, lane = t & 63;
    const int l15 = lane & 15, quad = lane >> 4;
    const int batch = blockIdx.x & 7;           // XCD spread: panels stay in one L2
    const int m0 = (blockIdx.x >> 3) * MT;
    const int kw = wave * KW;

    const uint16_t* Bp = Btb + (size_t)batch * BBS;
    const uint32_t* Hp = HT + (size_t)batch * (N_ / 32) * E_;

    f32x4 acc[18];
#pragma unroll
    for (int i = 0; i < 18; ++i) acc[i] = (f32x4){0.f, 0.f, 0.f, 0.f};

    // double-buffered operand regs — indexed ONLY with literal 0/1
    float    af0[16], af1[16];      // MODE 0: two 16-row groups x 8
    uint32_t aw0[2], aw1_[2];       // MODE 1
    uint4    ax0[2], ax1[2];        // MODE 2
    bf16x8   bf0[9], bf1[9];

    auto loadA = [&](int k0, int buf) __attribute__((always_inline)) {
        if constexpr (MODE == 0) {
            float* dst = buf ? af1 : af0;
#pragma unroll
            for (int g = 0; g < 2; ++g) {
                const float* ap = Ax + ((size_t)batch * N_ + m0 + g * 16 + l15) * C_ + k0 + quad * 8;
                const float4 f0 = *(const float4*)ap;
                const float4 f1 = *(const float4*)(ap + 4);
                dst[g * 8 + 0] = f0.x; dst[g * 8 + 1] = f0.y; dst[g * 8 + 2] = f0.z; dst[g * 8 + 3] = f0.w;
                dst[g * 8 + 4] = f1.x; dst[g * 8 + 5] = f1.y; dst[g * 8 + 6] = f1.z; dst[g * 8 + 7] = f1.w;
            }
        } else if constexpr (MODE == 1) {
            uint32_t* dst = buf ? aw1_ : aw0;
            const uint32_t* p = Hp + (size_t)(k0 >> 5) * E_ + m0 + l15;
            dst[0] = p[0];
            dst[1] = p[16];
        } else {
            uint4* dst = buf ? ax1 : ax0;
            const uint32_t* p = Hp + (size_t)(m0 >> 5) * E_ + k0 + quad * 8;
            dst[0] = *(const uint4*)p;
            dst[1] = *(const uint4*)(p + 4);
        }
    };
    auto loadB = [&](int k0, int buf) __attribute__((always_inline)) {
        bf16x8* dst = buf ? bf1 : bf0;
#pragma unroll
        for (int j = 0; j < 9; ++j)
            dst[j] = *(const bf16x8*)&Bp[(size_t)(j * 16 + l15) * K + k0 + quad * 8];
    };
    auto compute = [&](int buf) __attribute__((always_inline)) {
        bf16x8 a0, a1;
        if constexpr (MODE == 0) {
            const float* src = buf ? af1 : af0;
#pragma unroll
            for (int jj = 0; jj < 8; ++jj) {
                a0[jj] = (short)bf16_rne(src[jj]);
                a1[jj] = (short)bf16_rne(src[8 + jj]);
            }
        } else if constexpr (MODE == 1) {
            const uint32_t* src = buf ? aw1_ : aw0;
            const int base = quad * 8;
#pragma unroll
            for (int jj = 0; jj < 8; ++jj) {
                a0[jj] = (short)(((src[0] >> (base + jj)) & 1u) ? 0x3F80 : 0);
                a1[jj] = (short)(((src[1] >> (base + jj)) & 1u) ? 0x3F80 : 0);
            }
        } else {
            const uint4* src = buf ? ax1 : ax0;
            const uint32_t u[8] = {src[0].x, src[0].y, src[0].z, src[0].w,
                                   src[1].x, src[1].y, src[1].z, src[1].w};
#pragma unroll
            for (int jj = 0; jj < 8; ++jj) {
                a0[jj] = (short)(((u[jj] >> l15) & 1u) ? 0x3F80 : 0);
                a1[jj] = (short)(((u[jj] >> (16 + l15)) & 1u) ? 0x3F80 : 0);
            }
        }
        const bf16x8* bsrc = buf ? bf1 : bf0;
#pragma unroll
        for (int j = 0; j < 9; ++j) {
            acc[j]     = __builtin_amdgcn_mfma_f32_16x16x32_bf16(a0, bsrc[j], acc[j],     0, 0, 0);
            acc[9 + j] = __builtin_amdgcn_mfma_f32_16x16x32_bf16(a1, bsrc[j], acc[9 + j], 0, 0, 0);
        }
    };

    loadA(kw, 0); loadB(kw, 0);
#pragma unroll 1
    for (int s = 0; s < SW; s += 2) {
        if (s + 1 < SW) { loadA(kw + (s + 1) * KT, 1); loadB(kw + (s + 1) * KT, 1); }
        compute(0);
        if (s + 1 < SW) {
            if (s + 2 < SW) { loadA(kw + (s + 2) * KT, 0); loadB(kw + (s + 2) * KT, 0); }
            compute(1);
        }
    }

    // ---- cross-wave K reduction (3 barriers total) ----
    auto stR = [&](int base) __attribute__((always_inline)) {
#pragma unroll
        for (int g = 0; g < 2; ++g)
#pragma unroll
            for (int j = 0; j < 9; ++j)
#pragma unroll
                for (int r = 0; r < 4; ++r)
                    R[base + (g * 16 + quad * 4 + r) * LRF + j * 16 + l15] = acc[g * 9 + j][r];
    };
    auto ldR = [&](int base) __attribute__((always_inline)) {
#pragma unroll
        for (int g = 0; g < 2; ++g)
#pragma unroll
            for (int j = 0; j < 9; ++j)
#pragma unroll
                for (int r = 0; r < 4; ++r)
                    acc[g * 9 + j][r] += R[base + (g * 16 + quad * 4 + r) * LRF + j * 16 + l15];
    };
    if (wave == 1) stR(0);
    if (wave == 3) stR(32 * LRF);
    __syncthreads();
    if (wave == 0) ldR(0);
    if (wave == 2) ldR(32 * LRF);
    __syncthreads();
    if (wave == 2) stR(0);
    __syncthreads();
    if (wave != 0) return;
    ldR(0);

    // ---- epilogue (wave 0) ----
    float mul[2][4];
    if constexpr (MODE != 0) {
#pragma unroll
        for (int g = 0; g < 2; ++g)
#pragma unroll
            for (int r = 0; r < 4; ++r) {
                float sv = __shfl(acc[g * 9 + 8][r], lane & 48);  // lane quad*16 holds col 128
                mul[g][r] = (sv > 0.f) ? 1.f / sv : 0.f;
            }
    }
#pragma unroll
    for (int g = 0; g < 2; ++g) {
        const int row = m0 + g * 16 + quad * 4;
        if constexpr (MODE == 2) {
            float* op = outF + ((size_t)batch * N_ + row) * C_;
#pragma unroll
            for (int j = 0; j < 8; ++j) {
                int c = j * 16 + l15;
#pragma unroll
                for (int r = 0; r < 4; ++r) op[(size_t)r * C_ + c] = acc[g * 9 + j][r] * mul[g][r];
            }
        } else {
#pragma unroll
            for (int j = 0; j < 8; ++j) {
                int c = j * 16 + l15;
                float v0, v1, v2, v3;
                if constexpr (MODE == 0) {
                    float bb = bias[c];
                    v0 = acc[g * 9 + j][0] + bb; v1 = acc[g * 9 + j][1] + bb;
                    v2 = acc[g * 9 + j][2] + bb; v3 = acc[g * 9 + j][3] + bb;
                } else {
                    v0 = acc[g * 9 + j][0] * mul[g][0]; v1 = acc[g * 9 + j][1] * mul[g][1];
                    v2 = acc[g * 9 + j][2] * mul[g][2]; v3 = acc[g * 9 + j][3] * mul[g][3];
                }
                uint32_t q0 = (uint32_t)bf16_rne(v0) | ((uint32_t)bf16_rne(v1) << 16);
                uint32_t q1 = (uint32_t)bf16_rne(v2) | ((uint32_t)bf16_rne(v3) << 16);
                uint16_t* op = outT + ((size_t)batch * CN + c) * OLD + row;
                *(uint2*)op = make_uint2(q0, q1);
            }
        }
    }
}

// ---------------------------------------------------------------------------
extern "C" void kernel_launch(void* const* d_in, const int* in_sizes, int n_in,
                              void* d_out, int out_size, void* d_ws, size_t ws_size,
                              hipStream_t stream) {
    const float* x    = (const float*)d_in[0];   // [8,4096,128]
    const float* H    = (const float*)d_in[1];   // [8,4096,2048]
    const float* W    = (const float*)d_in[2];   // [128,128]
    const float* bias = (const float*)d_in[3];   // [128]
    float* out = (float*)d_out;                  // [8,4096,128]

    // ws (~12.8 MB): HT (8 MB) | WTb (36 KB) | ebfT (4.7 MB)
    uint32_t* HT   = (uint32_t*)d_ws;
    uint16_t* WTb  = (uint16_t*)(HT + HT_E);
    uint16_t* ebfT = WTb + WT_E;
    uint16_t* xwbT = (uint16_t*)d_out;           // d_out is dead scratch until e2v

    pack_kernel<<<dim3(8192), dim3(256), 0, stream>>>(H, HT);
    prep_kernel<<<dim3(1024), dim3(256), 0, stream>>>(W, WTb, (uint32_t*)xwbT, (uint32_t*)ebfT);
    gemm_k<0><<<dim3(8 * (N_ / MT)), dim3(256), 0, stream>>>(x, nullptr, WTb, bias, xwbT, nullptr);
    gemm_k<1><<<dim3(8 * (E_ / MT)), dim3(256), 0, stream>>>(nullptr, HT, xwbT, nullptr, ebfT, nullptr);
    gemm_k<2><<<dim3(8 * (N_ / MT)), dim3(256), 0, stream>>>(nullptr, HT, ebfT, nullptr, nullptr, out);
}

// Round 7
// 513.938 us; speedup vs baseline: 1.6773x; 1.0200x over previous
//
#include <hip/hip_runtime.h>
#include <stdint.h>

// Problem constants
constexpr int B_ = 8, N_ = 4096, E_ = 2048, C_ = 128;
constexpr int CN = 144;   // 128 channels + 1 ones-col + 15 pad
constexpr int KT = 32;    // K per MFMA step
constexpr int MT = 64;    // M rows per block (4 x 16-row groups, all owned by every wave)
constexpr int NWK = 4;    // K-split across the 4 waves of a block
constexpr int LRF = 145;  // reduction LDS row stride (floats)

typedef short bf16x8 __attribute__((ext_vector_type(8)));
typedef float f32x4  __attribute__((ext_vector_type(4)));

__device__ inline uint16_t bf16_rne(float f) {
    uint32_t u = __builtin_bit_cast(uint32_t, f);
    return (uint16_t)((u + 0x7FFFu + ((u >> 16) & 1u)) >> 16);
}

constexpr size_t HT_E  = (size_t)B_ * (N_ / 32) * E_;  // 2M dwords = 8 MB
constexpr size_t WT_E  = (size_t)CN * C_;
constexpr size_t EBF_E = (size_t)B_ * CN * E_;

// ---------------------------------------------------------------------------
// pack: H (fp32 0/1) -> HT[b][n/32][e], bit i of word = H[b][32*(n/32)+i][e].
// HBM-bound: reads the irreducible 268 MB once.
// ---------------------------------------------------------------------------
__global__ void pack_kernel(const float* __restrict__ H, uint32_t* __restrict__ HT) {
    const int t  = threadIdx.x;
    const int eg = blockIdx.x & 7;
    const int ng = (blockIdx.x >> 3) & 127;
    const int b  = blockIdx.x >> 10;
    const int e  = eg * 256 + t;
    const float* hp = H + ((size_t)b * N_ + ng * 32) * E_ + e;
    uint32_t w = 0;
#pragma unroll
    for (int i = 0; i < 32; ++i) w |= (hp[(size_t)i * E_] > 0.5f) ? (1u << i) : 0u;
    HT[((size_t)b * (N_ / 32) + ng) * E_ + e] = w;
}

// ---------------------------------------------------------------------------
// prep: WTb = bf16(W^T) padded to 144 rows; constant rows 128..143 of xwbT
// (in d_out) and ebfT (ws): row 128 = 1.0 (ones-col -> s_e / d_n), rest 0.
// ---------------------------------------------------------------------------
__global__ void prep_kernel(const float* __restrict__ W, uint16_t* __restrict__ WTb,
                            uint32_t* __restrict__ xwbT32, uint32_t* __restrict__ ebfT32) {
    const int NW = (int)WT_E;                  // 18432
    const int NX = B_ * 16 * (N_ / 2);         // 262144 dwords
    const int NE = B_ * 16 * (E_ / 2);         // 131072 dwords
    int stride = gridDim.x * blockDim.x;
    for (int i = blockIdx.x * blockDim.x + threadIdx.x; i < NW + NX + NE; i += stride) {
        if (i < NW) {
            int c = i >> 7, k = i & 127;
            WTb[i] = bf16_rne((c < C_) ? W[k * C_ + c] : 0.f);
        } else if (i < NW + NX) {
            int j = i - NW;
            int b = j >> 15, rr = j & 32767;
            int r = rr >> 11, n2 = rr & 2047;
            xwbT32[((size_t)b * CN + (C_ + r)) * (N_ / 2) + n2] = (r == 0) ? 0x3F803F80u : 0u;
        } else {
            int j = i - NW - NX;
            int b = j >> 14, rr = j & 16383;
            int r = rr >> 10, e2 = rr & 1023;
            ebfT32[((size_t)b * CN + (C_ + r)) * (E_ / 2) + e2] = (r == 0) ? 0x3F803F80u : 0u;
        }
    }
}

// ---------------------------------------------------------------------------
// Barrier-free MFMA GEMM, MT=64: every wave accumulates ALL 64 block rows
// (4 m-groups x 9 col-tiles = 36 accs) over its K quarter -> each B byte feeds
// 4x the MFMAs of round 6, halving chip-wide panel traffic to ~300 MB.
// B double-buffered (literal-indexed), A single-buffered (L1-resident bits,
// reloaded immediately after frag build). 3-barrier LDS reduction at end.
//  MODE 0 (fc) : A = x fp32,    B = WTb,  out bf16 C^T xwbT (+bias)
//  MODE 1 (v2e): A = H^T bits,  B = xwbT, out bf16 C^T ebfT (x 1/s_e)
//  MODE 2 (e2v): A = H bits,    B = ebfT, out fp32 row-major (x 1/d_n)
// ---------------------------------------------------------------------------
template <int MODE>
__global__ __launch_bounds__(256, 2)
void gemm_k(const float* __restrict__ Ax, const uint32_t* __restrict__ HT,
            const uint16_t* __restrict__ Btb, const float* __restrict__ bias,
            uint16_t* __restrict__ outT, float* __restrict__ outF) {
    constexpr int K  = (MODE == 0) ? C_ : (MODE == 1) ? N_ : E_;
    constexpr int KW = K / NWK;                 // per-wave K chunk
    constexpr int SW = KW / KT;                 // 1 / 32 / 16 iterations
    constexpr size_t BBS = (MODE == 0) ? 0 : (size_t)CN * K;
    constexpr int OLD = (MODE == 0) ? N_ : E_;

    __shared__ float R[2 * 64 * LRF];           // two 64x144 reduction regions (74 KB)

    const int t = threadIdx.x, wave = t >> 6, lane = t & 63;
    const int l15 = lane & 15, quad = lane >> 4;
    const int batch = blockIdx.x & 7;           // XCD spread: panels stay in one L2
    const int m0 = (blockIdx.x >> 3) * MT;
    const int kwv = wave * KW;

    const uint16_t* Bp = Btb + (size_t)batch * BBS;
    const uint32_t* Hp = HT + (size_t)batch * (N_ / 32) * E_;

    f32x4 acc[36];
#pragma unroll
    for (int i = 0; i < 36; ++i) acc[i] = (f32x4){0.f, 0.f, 0.f, 0.f};

    // single-buffered A state; double-buffered B (literal indices only)
    float    af[32];                // MODE 0: 4 groups x 8
    uint32_t aw[4];                 // MODE 1: one word per 16-row group
    uint4    axl[2], axh[2];        // MODE 2: two n-word-rows x 8 e-words
    bf16x8   bf0[9], bf1[9];

    auto loadA = [&](int k0) __attribute__((always_inline)) {
        if constexpr (MODE == 0) {
#pragma unroll
            for (int g = 0; g < 4; ++g) {
                const float* ap = Ax + ((size_t)batch * N_ + m0 + g * 16 + l15) * C_ + k0 + quad * 8;
                const float4 f0 = *(const float4*)ap;
                const float4 f1 = *(const float4*)(ap + 4);
                af[g * 8 + 0] = f0.x; af[g * 8 + 1] = f0.y; af[g * 8 + 2] = f0.z; af[g * 8 + 3] = f0.w;
                af[g * 8 + 4] = f1.x; af[g * 8 + 5] = f1.y; af[g * 8 + 6] = f1.z; af[g * 8 + 7] = f1.w;
            }
        } else if constexpr (MODE == 1) {
            const uint32_t* p = Hp + (size_t)(k0 >> 5) * E_ + m0 + l15;
            aw[0] = p[0]; aw[1] = p[16]; aw[2] = p[32]; aw[3] = p[48];
        } else {
            const uint32_t* p = Hp + (size_t)(m0 >> 5) * E_ + k0 + quad * 8;
            axl[0] = *(const uint4*)p;        axh[0] = *(const uint4*)(p + 4);
            axl[1] = *(const uint4*)(p + E_); axh[1] = *(const uint4*)(p + E_ + 4);
        }
    };
    auto loadB = [&](int k0, int buf) __attribute__((always_inline)) {
        bf16x8* dst = buf ? bf1 : bf0;
#pragma unroll
        for (int j = 0; j < 9; ++j)
            dst[j] = *(const bf16x8*)&Bp[(size_t)(j * 16 + l15) * K + k0 + quad * 8];
    };
    auto mkfrag = [&](int g) __attribute__((always_inline)) -> bf16x8 {
        bf16x8 v;
        if constexpr (MODE == 0) {
#pragma unroll
            for (int jj = 0; jj < 8; ++jj) v[jj] = (short)bf16_rne(af[g * 8 + jj]);
        } else if constexpr (MODE == 1) {
            const uint32_t w = aw[g];
            const int base = quad * 8;
#pragma unroll
            for (int jj = 0; jj < 8; ++jj)
                v[jj] = (short)(((w >> (base + jj)) & 1u) ? 0x3F80 : 0);
        } else {
            const int row = g >> 1, bit = (g & 1) * 16 + l15;
            const uint32_t u[8] = {axl[row].x, axl[row].y, axl[row].z, axl[row].w,
                                   axh[row].x, axh[row].y, axh[row].z, axh[row].w};
#pragma unroll
            for (int jj = 0; jj < 8; ++jj)
                v[jj] = (short)(((u[jj] >> bit) & 1u) ? 0x3F80 : 0);
        }
        return v;
    };
    auto mfma_all = [&](int buf) __attribute__((always_inline)) {
        bf16x8 a0 = mkfrag(0), a1 = mkfrag(1), a2 = mkfrag(2), a3 = mkfrag(3);
        const bf16x8* b = buf ? bf1 : bf0;
#pragma unroll
        for (int j = 0; j < 9; ++j) {
            acc[j]      = __builtin_amdgcn_mfma_f32_16x16x32_bf16(a0, b[j], acc[j],      0, 0, 0);
            acc[9 + j]  = __builtin_amdgcn_mfma_f32_16x16x32_bf16(a1, b[j], acc[9 + j],  0, 0, 0);
            acc[18 + j] = __builtin_amdgcn_mfma_f32_16x16x32_bf16(a2, b[j], acc[18 + j], 0, 0, 0);
            acc[27 + j] = __builtin_amdgcn_mfma_f32_16x16x32_bf16(a3, b[j], acc[27 + j], 0, 0, 0);
        }
    };

    loadA(kwv); loadB(kwv, 0);
#pragma unroll 1
    for (int s = 0; s < SW; s += 2) {
        if (s + 1 < SW) loadB(kwv + (s + 1) * KT, 1);
        {
            bf16x8 a0 = mkfrag(0), a1 = mkfrag(1), a2 = mkfrag(2), a3 = mkfrag(3);
            if (s + 1 < SW) loadA(kwv + (s + 1) * KT);   // A regs free after frag build
#pragma unroll
            for (int j = 0; j < 9; ++j) {
                acc[j]      = __builtin_amdgcn_mfma_f32_16x16x32_bf16(a0, bf0[j], acc[j],      0, 0, 0);
                acc[9 + j]  = __builtin_amdgcn_mfma_f32_16x16x32_bf16(a1, bf0[j], acc[9 + j],  0, 0, 0);
                acc[18 + j] = __builtin_amdgcn_mfma_f32_16x16x32_bf16(a2, bf0[j], acc[18 + j], 0, 0, 0);
                acc[27 + j] = __builtin_amdgcn_mfma_f32_16x16x32_bf16(a3, bf0[j], acc[27 + j], 0, 0, 0);
            }
        }
        if (s + 1 < SW) {
            if (s + 2 < SW) loadB(kwv + (s + 2) * KT, 0);
            bf16x8 a0 = mkfrag(0), a1 = mkfrag(1), a2 = mkfrag(2), a3 = mkfrag(3);
            if (s + 2 < SW) loadA(kwv + (s + 2) * KT);
#pragma unroll
            for (int j = 0; j < 9; ++j) {
                acc[j]      = __builtin_amdgcn_mfma_f32_16x16x32_bf16(a0, bf1[j], acc[j],      0, 0, 0);
                acc[9 + j]  = __builtin_amdgcn_mfma_f32_16x16x32_bf16(a1, bf1[j], acc[9 + j],  0, 0, 0);
                acc[18 + j] = __builtin_amdgcn_mfma_f32_16x16x32_bf16(a2, bf1[j], acc[18 + j], 0, 0, 0);
                acc[27 + j] = __builtin_amdgcn_mfma_f32_16x16x32_bf16(a3, bf1[j], acc[27 + j], 0, 0, 0);
            }
        }
    }

    // ---- cross-wave K reduction (3 barriers total) ----
    auto stR = [&](int base) __attribute__((always_inline)) {
#pragma unroll
        for (int g = 0; g < 4; ++g)
#pragma unroll
            for (int j = 0; j < 9; ++j)
#pragma unroll
                for (int r = 0; r < 4; ++r)
                    R[base + (g * 16 + quad * 4 + r) * LRF + j * 16 + l15] = acc[g * 9 + j][r];
    };
    auto ldR = [&](int base) __attribute__((always_inline)) {
#pragma unroll
        for (int g = 0; g < 4; ++g)
#pragma unroll
            for (int j = 0; j < 9; ++j)
#pragma unroll
                for (int r = 0; r < 4; ++r)
                    acc[g * 9 + j][r] += R[base + (g * 16 + quad * 4 + r) * LRF + j * 16 + l15];
    };
    if (wave == 1) stR(0);
    if (wave == 3) stR(64 * LRF);
    __syncthreads();
    if (wave == 0) ldR(0);
    if (wave == 2) ldR(64 * LRF);
    __syncthreads();
    if (wave == 2) stR(0);
    __syncthreads();
    if (wave != 0) return;
    ldR(0);

    // ---- epilogue (wave 0) ----
    float mul[4][4];
    if constexpr (MODE != 0) {
#pragma unroll
        for (int g = 0; g < 4; ++g)
#pragma unroll
            for (int r = 0; r < 4; ++r) {
                float sv = __shfl(acc[g * 9 + 8][r], lane & 48);  // lane quad*16 holds col 128
                mul[g][r] = (sv > 0.f) ? 1.f / sv : 0.f;
            }
    }
#pragma unroll
    for (int g = 0; g < 4; ++g) {
        const int row = m0 + g * 16 + quad * 4;
        if constexpr (MODE == 2) {
            float* op = outF + ((size_t)batch * N_ + row) * C_;
#pragma unroll
            for (int j = 0; j < 8; ++j) {
                int c = j * 16 + l15;
#pragma unroll
                for (int r = 0; r < 4; ++r) op[(size_t)r * C_ + c] = acc[g * 9 + j][r] * mul[g][r];
            }
        } else {
#pragma unroll
            for (int j = 0; j < 8; ++j) {
                int c = j * 16 + l15;
                float v0, v1, v2, v3;
                if constexpr (MODE == 0) {
                    float bb = bias[c];
                    v0 = acc[g * 9 + j][0] + bb; v1 = acc[g * 9 + j][1] + bb;
                    v2 = acc[g * 9 + j][2] + bb; v3 = acc[g * 9 + j][3] + bb;
                } else {
                    v0 = acc[g * 9 + j][0] * mul[g][0]; v1 = acc[g * 9 + j][1] * mul[g][1];
                    v2 = acc[g * 9 + j][2] * mul[g][2]; v3 = acc[g * 9 + j][3] * mul[g][3];
                }
                uint32_t q0 = (uint32_t)bf16_rne(v0) | ((uint32_t)bf16_rne(v1) << 16);
                uint32_t q1 = (uint32_t)bf16_rne(v2) | ((uint32_t)bf16_rne(v3) << 16);
                uint16_t* op = outT + ((size_t)batch * CN + c) * OLD + row;
                *(uint2*)op = make_uint2(q0, q1);
            }
        }
    }
}

// ---------------------------------------------------------------------------
extern "C" void kernel_launch(void* const* d_in, const int* in_sizes, int n_in,
                              void* d_out, int out_size, void* d_ws, size_t ws_size,
                              hipStream_t stream) {
    const float* x    = (const float*)d_in[0];   // [8,4096,128]
    const float* H    = (const float*)d_in[1];   // [8,4096,2048]
    const float* W    = (const float*)d_in[2];   // [128,128]
    const float* bias = (const float*)d_in[3];   // [128]
    float* out = (float*)d_out;                  // [8,4096,128]

    // ws (~12.8 MB): HT (8 MB) | WTb (36 KB) | ebfT (4.7 MB)
    uint32_t* HT   = (uint32_t*)d_ws;
    uint16_t* WTb  = (uint16_t*)(HT + HT_E);
    uint16_t* ebfT = WTb + WT_E;
    uint16_t* xwbT = (uint16_t*)d_out;           // d_out is dead scratch until e2v

    pack_kernel<<<dim3(8192), dim3(256), 0, stream>>>(H, HT);
    prep_kernel<<<dim3(1024), dim3(256), 0, stream>>>(W, WTb, (uint32_t*)xwbT, (uint32_t*)ebfT);
    gemm_k<0><<<dim3(8 * (N_ / MT)), dim3(256), 0, stream>>>(x, nullptr, WTb, bias, xwbT, nullptr);
    gemm_k<1><<<dim3(8 * (E_ / MT)), dim3(256), 0, stream>>>(nullptr, HT, xwbT, nullptr, ebfT, nullptr);
    gemm_k<2><<<dim3(8 * (N_ / MT)), dim3(256), 0, stream>>>(nullptr, HT, ebfT, nullptr, nullptr, out);
}